// Round 7
// baseline (566.816 us; speedup 1.0000x reference)
//
#include <hip/hip_runtime.h>
#include <hip/hip_bf16.h>

#define GN 8192
#define KD 256
#define OD 64
#define LOG2E 1.44269504f
#define MSTR 257   // mask LDS row stride in words -> conflict-free across tn

typedef __attribute__((ext_vector_type(8))) short bf16x8;
typedef __attribute__((ext_vector_type(4))) float f32x4;

__device__ __forceinline__ float fexp2(float x) {
#if __has_builtin(__builtin_amdgcn_exp2f)
  return __builtin_amdgcn_exp2f(x);
#else
  return exp2f(x);
#endif
}

// ---------------------------------------------------------------------------
// Kernel 0: pack adj (int32 {0,1}, 256 MB) into a bitmask (8 MB).
// Pure streaming: wave-wide coalesced load + ballot + 8B store from lane 0.
// This is the ONLY kernel that touches adj -> runs at fill-kernel BW.
// ---------------------------------------------------------------------------
__global__ __launch_bounds__(256) void gat_k0(
    const int* __restrict__ adj, unsigned long long* __restrict__ mask)
{
  const long stride = (long)gridDim.x * 256;
  long t = (long)blockIdx.x * 256 + threadIdx.x;
  const int lane = threadIdx.x & 63;
#pragma unroll 4
  for (int it = 0; it < 64; ++it, t += stride) {
    unsigned long long m = __ballot(adj[t] > 0);
    if (lane == 0) mask[t >> 6] = m;
  }
}

// ---------------------------------------------------------------------------
// Kernel 1: h = input @ W (fp32). Emits hT (bf16 [OD][GN]), f1p/f2p fp32
// pre-scaled by log2(e), and the 3 scalar e-outputs.
// ---------------------------------------------------------------------------
__global__ __launch_bounds__(256) void gat_k1(
    const float* __restrict__ input, const float* __restrict__ W,
    const float* __restrict__ a, __hip_bfloat16* __restrict__ hT,
    float* __restrict__ f1p, float* __restrict__ f2p, float* __restrict__ out)
{
  __shared__ float Wl[KD * OD];        // 64 KB, [k][c]
  __shared__ float inT[KD * 33];       // [k][r], pad 33
  __shared__ float red1[8][32];
  __shared__ float red2[8][32];
  __shared__ float s1row[32];
  __shared__ float s2row[32];

  const int tid = threadIdx.x;
  const int i0 = blockIdx.x * 32;

  for (int idx = tid; idx < KD * OD / 4; idx += 256)
    ((float4*)Wl)[idx] = ((const float4*)W)[idx];

#pragma unroll
  for (int it = 0; it < 8; ++it) {
    int idx = tid + it * 256;
    int r = idx >> 6, k4 = idx & 63;
    float4 v = *(const float4*)(input + (long)(i0 + r) * KD + k4 * 4);
    inT[(k4 * 4 + 0) * 33 + r] = v.x;
    inT[(k4 * 4 + 1) * 33 + r] = v.y;
    inT[(k4 * 4 + 2) * 33 + r] = v.z;
    inT[(k4 * 4 + 3) * 33 + r] = v.w;
  }
  __syncthreads();

  const int r = tid & 31;
  const int cg = tid >> 5;
  float acc[8];
#pragma unroll
  for (int c = 0; c < 8; ++c) acc[c] = 0.f;

#pragma unroll 4
  for (int k = 0; k < KD; ++k) {
    float inv = inT[k * 33 + r];
    float4 wa = *(const float4*)&Wl[k * 64 + cg * 8];
    float4 wb = *(const float4*)&Wl[k * 64 + cg * 8 + 4];
    acc[0] += inv * wa.x; acc[1] += inv * wa.y;
    acc[2] += inv * wa.z; acc[3] += inv * wa.w;
    acc[4] += inv * wb.x; acc[5] += inv * wb.y;
    acc[6] += inv * wb.z; acc[7] += inv * wb.w;
  }

#pragma unroll
  for (int c = 0; c < 8; ++c)
    hT[(long)(cg * 8 + c) * GN + i0 + r] = __float2bfloat16(acc[c]);

  float s1 = 0.f, s2 = 0.f;
#pragma unroll
  for (int c = 0; c < 8; ++c) {
    s1 += acc[c] * a[cg * 8 + c];
    s2 += acc[c] * a[OD + cg * 8 + c];
  }
  red1[cg][r] = s1; red2[cg][r] = s2;
  __syncthreads();
  if (tid < 32) {
    float f1 = 0.f, f2 = 0.f;
#pragma unroll
    for (int g = 0; g < 8; ++g) { f1 += red1[g][tid]; f2 += red2[g][tid]; }
    s1row[tid] = f1; s2row[tid] = f2;
    f1p[i0 + tid] = f1 * LOG2E;
    f2p[i0 + tid] = f2 * LOG2E;
  }
  __syncthreads();
  if (blockIdx.x == 0 && tid == 0) {
    float e12 = s1row[1] + s2row[2];
    float e13 = s1row[1] + s2row[3];
    float e32 = s1row[3] + s2row[2];
    out[(long)GN * OD + 0] = fmaxf(e12, 0.01f * e12);
    out[(long)GN * OD + 1] = fmaxf(e13, 0.01f * e13);
    out[(long)GN * OD + 2] = fmaxf(e32, 0.01f * e32);
  }
}

// ---------------------------------------------------------------------------
// Kernel 2: fused mask+softmax(no-max)+alpha@h from the BITMASK.
// Block = 16 rows x all 8192 j; wave = 16 rows x 2048-j quarter.
// LDS: f2 (32 KB, staged once) + mask strip (16 rows x 1 KB, staged once,
// stride-257 words -> conflict-free). Main loop: LDS reads + L2-resident hT
// B-frags (2-deep register rotation) + VALU w-gen + MFMA. No barriers,
// no global adj traffic. 512 blocks, 3 blocks/CU.
// ---------------------------------------------------------------------------
__global__ __launch_bounds__(256, 3) void gat_k2(
    const unsigned* __restrict__ maskG, const __hip_bfloat16* __restrict__ hT,
    const float* __restrict__ f1p, const float* __restrict__ f2p,
    float* __restrict__ out)
{
  __shared__ float f2l[GN];                 // 32 KB; epilogue overlays pb/sb here
  __shared__ unsigned maskL[16 * MSTR];     // 16.4 KB

  const int tid = threadIdx.x;
  const int lane = tid & 63;
  const int wv = tid >> 6;             // j-quarter 0..3
  const int tn = lane & 15;            // MFMA m/n index (row)
  const int quad = lane >> 4;          // MFMA k-quad
  const int i0 = blockIdx.x * 16;

  // stage f2 (32 KB) and this block's mask strip (16 rows x 256 words)
  for (int i = tid; i < GN / 4; i += 256)
    ((float4*)f2l)[i] = ((const float4*)f2p)[i];
#pragma unroll
  for (int it = 0; it < 16; ++it) {
    int idx = tid + it * 256;                 // 0..4095
    int r = idx >> 8, w = idx & 255;
    maskL[r * MSTR + w] = maskG[(long)(i0 + r) * 256 + w];
  }

  const float f1r = f1p[i0 + tn];
  __syncthreads();

  const int jq = wv * 2048;
  const __hip_bfloat16* hp = hT + (long)tn * GN + jq + quad * 8;
  const float* f2q = f2l + jq + quad * 8;
  const int mbase = tn * MSTR + wv * 64;    // + s -> word for this lane's slice

  f32x4 acc[4];
#pragma unroll
  for (int nf = 0; nf < 4; ++nf) acc[nf] = (f32x4){0.f, 0.f, 0.f, 0.f};
  f32x4 accS = (f32x4){0.f, 0.f, 0.f, 0.f};

  bf16x8 ones;  // ones in column n==0 -> row sums via MFMA
  {
    short ov = (tn == 0) ? (short)0x3F80 : (short)0;
#pragma unroll
    for (int i = 0; i < 8; ++i) ones[i] = ov;
  }

  struct Bsl { bf16x8 b0, b1, b2, b3; };
  auto loadB = [&](int s) {
    Bsl r;
    r.b0 = *(const bf16x8*)(hp + 0 * 16 * (long)GN + s * 32);
    r.b1 = *(const bf16x8*)(hp + 1 * 16 * (long)GN + s * 32);
    r.b2 = *(const bf16x8*)(hp + 2 * 16 * (long)GN + s * 32);
    r.b3 = *(const bf16x8*)(hp + 3 * 16 * (long)GN + s * 32);
    return r;
  };

  Bsl Bb[2];
  Bb[0] = loadB(0);
  Bb[1] = loadB(1);

  for (int s = 0; s < 64; ++s) {
    Bsl cb = Bb[s & 1];
    if (s + 2 < 64) Bb[s & 1] = loadB(s + 2);

    const unsigned bits = (maskL[mbase + s] >> (quad * 8)) & 0xffu;
    const float4 f20 = *(const float4*)(f2q + s * 32);
    const float4 f21 = *(const float4*)(f2q + s * 32 + 4);

    float e0 = f1r + f20.x, e1 = f1r + f20.y, e2 = f1r + f20.z, e3 = f1r + f20.w;
    float e4 = f1r + f21.x, e5 = f1r + f21.y, e6 = f1r + f21.z, e7 = f1r + f21.w;
    float v0 = fexp2(fmaxf(e0, 0.01f * e0));
    float v1 = fexp2(fmaxf(e1, 0.01f * e1));
    float v2 = fexp2(fmaxf(e2, 0.01f * e2));
    float v3 = fexp2(fmaxf(e3, 0.01f * e3));
    float v4 = fexp2(fmaxf(e4, 0.01f * e4));
    float v5 = fexp2(fmaxf(e5, 0.01f * e5));
    float v6 = fexp2(fmaxf(e6, 0.01f * e6));
    float v7 = fexp2(fmaxf(e7, 0.01f * e7));
    v0 = (bits & 1u)   ? v0 : 0.f;
    v1 = (bits & 2u)   ? v1 : 0.f;
    v2 = (bits & 4u)   ? v2 : 0.f;
    v3 = (bits & 8u)   ? v3 : 0.f;
    v4 = (bits & 16u)  ? v4 : 0.f;
    v5 = (bits & 32u)  ? v5 : 0.f;
    v6 = (bits & 64u)  ? v6 : 0.f;
    v7 = (bits & 128u) ? v7 : 0.f;

    union { bf16x8 v; unsigned u[4]; } wf;
    wf.u[0] = __builtin_amdgcn_perm(__float_as_uint(v1), __float_as_uint(v0), 0x07060302u);
    wf.u[1] = __builtin_amdgcn_perm(__float_as_uint(v3), __float_as_uint(v2), 0x07060302u);
    wf.u[2] = __builtin_amdgcn_perm(__float_as_uint(v5), __float_as_uint(v4), 0x07060302u);
    wf.u[3] = __builtin_amdgcn_perm(__float_as_uint(v7), __float_as_uint(v6), 0x07060302u);

    acc[0] = __builtin_amdgcn_mfma_f32_16x16x32_bf16(wf.v, cb.b0, acc[0], 0, 0, 0);
    acc[1] = __builtin_amdgcn_mfma_f32_16x16x32_bf16(wf.v, cb.b1, acc[1], 0, 0, 0);
    acc[2] = __builtin_amdgcn_mfma_f32_16x16x32_bf16(wf.v, cb.b2, acc[2], 0, 0, 0);
    acc[3] = __builtin_amdgcn_mfma_f32_16x16x32_bf16(wf.v, cb.b3, acc[3], 0, 0, 0);
    accS   = __builtin_amdgcn_mfma_f32_16x16x32_bf16(wf.v, ones,  accS,   0, 0, 0);
  }

  // epilogue: overlay pb/sb on f2l (all f2/mask reads done), reduce quarters
  __syncthreads();
  float* pb = f2l;                 // [4][16][68]
  float* sb = f2l + 4 * 16 * 68;   // [4][16]
#pragma unroll
  for (int nf = 0; nf < 4; ++nf)
#pragma unroll
    for (int rgi = 0; rgi < 4; ++rgi)
      pb[(wv * 16 + quad * 4 + rgi) * 68 + nf * 16 + tn] = acc[nf][rgi];
  if (tn == 0) {
#pragma unroll
    for (int rgi = 0; rgi < 4; ++rgi)
      sb[wv * 16 + quad * 4 + rgi] = accS[rgi];
  }
  __syncthreads();
  for (int t = tid; t < 16 * OD; t += 256) {
    int rr = t >> 6, cc = t & 63;
    float num = pb[(0 * 16 + rr) * 68 + cc] + pb[(1 * 16 + rr) * 68 + cc] +
                pb[(2 * 16 + rr) * 68 + cc] + pb[(3 * 16 + rr) * 68 + cc];
    float den = sb[0 * 16 + rr] + sb[1 * 16 + rr] + sb[2 * 16 + rr] + sb[3 * 16 + rr];
    out[(long)(i0 + rr) * OD + cc] = num / den;
  }
}

extern "C" void kernel_launch(void* const* d_in, const int* in_sizes, int n_in,
                              void* d_out, int out_size, void* d_ws, size_t ws_size,
                              hipStream_t stream) {
  const float* input = (const float*)d_in[0];
  const int* adj     = (const int*)d_in[1];
  const float* W     = (const float*)d_in[2];
  const float* a     = (const float*)d_in[3];
  float* out = (float*)d_out;

  char* ws = (char*)d_ws;
  __hip_bfloat16* hT = (__hip_bfloat16*)ws;               // 1 MB
  float* f1p = (float*)(ws + (size_t)OD * GN * 2);        // 32 KB
  float* f2p = f1p + GN;                                  // 32 KB
  unsigned long long* mask = (unsigned long long*)(f2p + GN);  // 8 MB

  gat_k0<<<4096, 256, 0, stream>>>(adj, mask);
  gat_k1<<<256, 256, 0, stream>>>(input, W, a, hT, f1p, f2p, out);
  gat_k2<<<512, 256, 0, stream>>>((const unsigned*)mask, hT, f1p, f2p, out);
}

// Round 8
// 544.100 us; speedup vs baseline: 1.0417x; 1.0417x over previous
//
#include <hip/hip_runtime.h>
#include <hip/hip_bf16.h>

#define GN 8192
#define KD 256
#define OD 64
#define LOG2E 1.44269504f
#define MSTR 257   // mask LDS row stride in words -> conflict-free across tn

typedef __attribute__((ext_vector_type(8))) short bf16x8;
typedef __attribute__((ext_vector_type(4))) float f32x4;

__device__ __forceinline__ float fexp2(float x) {
#if __has_builtin(__builtin_amdgcn_exp2f)
  return __builtin_amdgcn_exp2f(x);
#else
  return exp2f(x);
#endif
}

// ---------------------------------------------------------------------------
// Kernel 0: pack adj (int32 {0,1}, 256 MB) into a bitmask (8 MB).
// Each block packs a CONTIGUOUS 64 KB segment (16384 ints) -> no page hops.
// Coalesced 1KB/wave loads; lane0 stores one u64 per wave (bit i = lane i,
// matching j%64 since segments are 64-aligned).
// ---------------------------------------------------------------------------
__global__ __launch_bounds__(256) void gat_k0(
    const int* __restrict__ adj, unsigned long long* __restrict__ mask)
{
  const long base = (long)blockIdx.x * 16384;
  const int lane = threadIdx.x & 63;
#pragma unroll 4
  for (int it = 0; it < 64; ++it) {
    long t = base + it * 256 + threadIdx.x;
    unsigned long long m = __ballot(adj[t] > 0);
    if (lane == 0) mask[t >> 6] = m;
  }
}

// ---------------------------------------------------------------------------
// Kernel 1: h = input @ W (fp32). Emits hTt (bf16, TILED [j/32][col][j%32] so
// k2's B-frag loads are contiguous), f1p/f2p fp32 pre-scaled by log2(e),
// and the 3 scalar e-outputs.
// ---------------------------------------------------------------------------
__global__ __launch_bounds__(256) void gat_k1(
    const float* __restrict__ input, const float* __restrict__ W,
    const float* __restrict__ a, __hip_bfloat16* __restrict__ hTt,
    float* __restrict__ f1p, float* __restrict__ f2p, float* __restrict__ out)
{
  __shared__ float Wl[KD * OD];        // 64 KB, [k][c]
  __shared__ float inT[KD * 33];       // [k][r], pad 33
  __shared__ float red1[8][32];
  __shared__ float red2[8][32];
  __shared__ float s1row[32];
  __shared__ float s2row[32];

  const int tid = threadIdx.x;
  const int i0 = blockIdx.x * 32;      // this block's 32 j-rows == one j-tile

  for (int idx = tid; idx < KD * OD / 4; idx += 256)
    ((float4*)Wl)[idx] = ((const float4*)W)[idx];

#pragma unroll
  for (int it = 0; it < 8; ++it) {
    int idx = tid + it * 256;
    int r = idx >> 6, k4 = idx & 63;
    float4 v = *(const float4*)(input + (long)(i0 + r) * KD + k4 * 4);
    inT[(k4 * 4 + 0) * 33 + r] = v.x;
    inT[(k4 * 4 + 1) * 33 + r] = v.y;
    inT[(k4 * 4 + 2) * 33 + r] = v.z;
    inT[(k4 * 4 + 3) * 33 + r] = v.w;
  }
  __syncthreads();

  const int r = tid & 31;
  const int cg = tid >> 5;
  float acc[8];
#pragma unroll
  for (int c = 0; c < 8; ++c) acc[c] = 0.f;

#pragma unroll 4
  for (int k = 0; k < KD; ++k) {
    float inv = inT[k * 33 + r];
    float4 wa = *(const float4*)&Wl[k * 64 + cg * 8];
    float4 wb = *(const float4*)&Wl[k * 64 + cg * 8 + 4];
    acc[0] += inv * wa.x; acc[1] += inv * wa.y;
    acc[2] += inv * wa.z; acc[3] += inv * wa.w;
    acc[4] += inv * wb.x; acc[5] += inv * wb.y;
    acc[6] += inv * wb.z; acc[7] += inv * wb.w;
  }

  // hTt[jb][col][jw]: jb = blockIdx (32-row tile), jw = r
#pragma unroll
  for (int c = 0; c < 8; ++c)
    hTt[(long)blockIdx.x * (OD * 32) + (cg * 8 + c) * 32 + r] =
        __float2bfloat16(acc[c]);

  float s1 = 0.f, s2 = 0.f;
#pragma unroll
  for (int c = 0; c < 8; ++c) {
    s1 += acc[c] * a[cg * 8 + c];
    s2 += acc[c] * a[OD + cg * 8 + c];
  }
  red1[cg][r] = s1; red2[cg][r] = s2;
  __syncthreads();
  if (tid < 32) {
    float f1 = 0.f, f2 = 0.f;
#pragma unroll
    for (int g = 0; g < 8; ++g) { f1 += red1[g][tid]; f2 += red2[g][tid]; }
    s1row[tid] = f1; s2row[tid] = f2;
    f1p[i0 + tid] = f1 * LOG2E;
    f2p[i0 + tid] = f2 * LOG2E;
  }
  __syncthreads();
  if (blockIdx.x == 0 && tid == 0) {
    float e12 = s1row[1] + s2row[2];
    float e13 = s1row[1] + s2row[3];
    float e32 = s1row[3] + s2row[2];
    out[(long)GN * OD + 0] = fmaxf(e12, 0.01f * e12);
    out[(long)GN * OD + 1] = fmaxf(e13, 0.01f * e13);
    out[(long)GN * OD + 2] = fmaxf(e32, 0.01f * e32);
  }
}

// ---------------------------------------------------------------------------
// Kernel 2: fused mask+softmax(no-max)+alpha@h from the BITMASK.
// B-frags from the TILED hTt: one slice's B tile (64 cols x 32 j = 4 KB) is
// CONTIGUOUS; each of the 4 loads/slice is a fully-coalesced 1KB/wave instr.
// Block = 16 rows x all 8192 j; wave = 16 rows x 2048-j quarter. No barriers
// in the main loop; 2-deep B register rotation. 512 blocks, 3 blocks/CU.
// ---------------------------------------------------------------------------
__global__ __launch_bounds__(256, 3) void gat_k2(
    const unsigned* __restrict__ maskG, const __hip_bfloat16* __restrict__ hTt,
    const float* __restrict__ f1p, const float* __restrict__ f2p,
    float* __restrict__ out)
{
  __shared__ float f2l[GN];                 // 32 KB; epilogue overlays pb/sb here
  __shared__ unsigned maskL[16 * MSTR];     // 16.4 KB

  const int tid = threadIdx.x;
  const int lane = tid & 63;
  const int wv = tid >> 6;             // j-quarter 0..3
  const int tn = lane & 15;            // MFMA m (row) / n (col) index
  const int quad = lane >> 4;          // MFMA k-quad
  const int i0 = blockIdx.x * 16;

  // stage f2 (32 KB) and this block's mask strip (16 rows x 256 words)
  for (int i = tid; i < GN / 4; i += 256)
    ((float4*)f2l)[i] = ((const float4*)f2p)[i];
#pragma unroll
  for (int it = 0; it < 16; ++it) {
    int idx = tid + it * 256;                 // 0..4095
    int r = idx >> 8, w = idx & 255;
    maskL[r * MSTR + w] = maskG[(long)(i0 + r) * 256 + w];
  }

  const float f1r = f1p[i0 + tn];
  __syncthreads();

  const int jq = wv * 2048;
  // B-frag base for this lane: slice s lives at hTt + (jq/32+s)*2048;
  // within a slice: col*32 + quad*8, col = nf*16+tn.
  const __hip_bfloat16* hp = hTt + (long)(jq / 32) * (OD * 32) + tn * 32 + quad * 8;
  const float* f2q = f2l + jq + quad * 8;
  const int mbase = tn * MSTR + wv * 64;    // + s -> mask word for this lane

  f32x4 acc[4];
#pragma unroll
  for (int nf = 0; nf < 4; ++nf) acc[nf] = (f32x4){0.f, 0.f, 0.f, 0.f};
  f32x4 accS = (f32x4){0.f, 0.f, 0.f, 0.f};

  bf16x8 ones;  // ones in column n==0 -> row sums via MFMA
  {
    short ov = (tn == 0) ? (short)0x3F80 : (short)0;
#pragma unroll
    for (int i = 0; i < 8; ++i) ones[i] = ov;
  }

  struct Bsl { bf16x8 b0, b1, b2, b3; };
  auto loadB = [&](int s) {
    Bsl r;
    r.b0 = *(const bf16x8*)(hp + (long)s * (OD * 32) + 0 * 16 * 32);
    r.b1 = *(const bf16x8*)(hp + (long)s * (OD * 32) + 1 * 16 * 32);
    r.b2 = *(const bf16x8*)(hp + (long)s * (OD * 32) + 2 * 16 * 32);
    r.b3 = *(const bf16x8*)(hp + (long)s * (OD * 32) + 3 * 16 * 32);
    return r;
  };

  Bsl Bb[2];
  Bb[0] = loadB(0);
  Bb[1] = loadB(1);

  for (int s = 0; s < 64; ++s) {
    Bsl cb = Bb[s & 1];
    if (s + 2 < 64) Bb[s & 1] = loadB(s + 2);

    const unsigned bits = (maskL[mbase + s] >> (quad * 8)) & 0xffu;
    const float4 f20 = *(const float4*)(f2q + s * 32);
    const float4 f21 = *(const float4*)(f2q + s * 32 + 4);

    float e0 = f1r + f20.x, e1 = f1r + f20.y, e2 = f1r + f20.z, e3 = f1r + f20.w;
    float e4 = f1r + f21.x, e5 = f1r + f21.y, e6 = f1r + f21.z, e7 = f1r + f21.w;
    float v0 = fexp2(fmaxf(e0, 0.01f * e0));
    float v1 = fexp2(fmaxf(e1, 0.01f * e1));
    float v2 = fexp2(fmaxf(e2, 0.01f * e2));
    float v3 = fexp2(fmaxf(e3, 0.01f * e3));
    float v4 = fexp2(fmaxf(e4, 0.01f * e4));
    float v5 = fexp2(fmaxf(e5, 0.01f * e5));
    float v6 = fexp2(fmaxf(e6, 0.01f * e6));
    float v7 = fexp2(fmaxf(e7, 0.01f * e7));
    v0 = (bits & 1u)   ? v0 : 0.f;
    v1 = (bits & 2u)   ? v1 : 0.f;
    v2 = (bits & 4u)   ? v2 : 0.f;
    v3 = (bits & 8u)   ? v3 : 0.f;
    v4 = (bits & 16u)  ? v4 : 0.f;
    v5 = (bits & 32u)  ? v5 : 0.f;
    v6 = (bits & 64u)  ? v6 : 0.f;
    v7 = (bits & 128u) ? v7 : 0.f;

    union { bf16x8 v; unsigned u[4]; } wf;
    wf.u[0] = __builtin_amdgcn_perm(__float_as_uint(v1), __float_as_uint(v0), 0x07060302u);
    wf.u[1] = __builtin_amdgcn_perm(__float_as_uint(v3), __float_as_uint(v2), 0x07060302u);
    wf.u[2] = __builtin_amdgcn_perm(__float_as_uint(v5), __float_as_uint(v4), 0x07060302u);
    wf.u[3] = __builtin_amdgcn_perm(__float_as_uint(v7), __float_as_uint(v6), 0x07060302u);

    acc[0] = __builtin_amdgcn_mfma_f32_16x16x32_bf16(wf.v, cb.b0, acc[0], 0, 0, 0);
    acc[1] = __builtin_amdgcn_mfma_f32_16x16x32_bf16(wf.v, cb.b1, acc[1], 0, 0, 0);
    acc[2] = __builtin_amdgcn_mfma_f32_16x16x32_bf16(wf.v, cb.b2, acc[2], 0, 0, 0);
    acc[3] = __builtin_amdgcn_mfma_f32_16x16x32_bf16(wf.v, cb.b3, acc[3], 0, 0, 0);
    accS   = __builtin_amdgcn_mfma_f32_16x16x32_bf16(wf.v, ones,  accS,   0, 0, 0);
  }

  // epilogue: overlay pb/sb on f2l (all f2/mask reads done), reduce quarters
  __syncthreads();
  float* pb = f2l;                 // [4][16][68]
  float* sb = f2l + 4 * 16 * 68;   // [4][16]
#pragma unroll
  for (int nf = 0; nf < 4; ++nf)
#pragma unroll
    for (int rgi = 0; rgi < 4; ++rgi)
      pb[(wv * 16 + quad * 4 + rgi) * 68 + nf * 16 + tn] = acc[nf][rgi];
  if (tn == 0) {
#pragma unroll
    for (int rgi = 0; rgi < 4; ++rgi)
      sb[wv * 16 + quad * 4 + rgi] = accS[rgi];
  }
  __syncthreads();
  for (int t = tid; t < 16 * OD; t += 256) {
    int rr = t >> 6, cc = t & 63;
    float num = pb[(0 * 16 + rr) * 68 + cc] + pb[(1 * 16 + rr) * 68 + cc] +
                pb[(2 * 16 + rr) * 68 + cc] + pb[(3 * 16 + rr) * 68 + cc];
    float den = sb[0 * 16 + rr] + sb[1 * 16 + rr] + sb[2 * 16 + rr] + sb[3 * 16 + rr];
    out[(long)(i0 + rr) * OD + cc] = num / den;
  }
}

extern "C" void kernel_launch(void* const* d_in, const int* in_sizes, int n_in,
                              void* d_out, int out_size, void* d_ws, size_t ws_size,
                              hipStream_t stream) {
  const float* input = (const float*)d_in[0];
  const int* adj     = (const int*)d_in[1];
  const float* W     = (const float*)d_in[2];
  const float* a     = (const float*)d_in[3];
  float* out = (float*)d_out;

  char* ws = (char*)d_ws;
  __hip_bfloat16* hTt = (__hip_bfloat16*)ws;              // 1 MB (tiled)
  float* f1p = (float*)(ws + (size_t)OD * GN * 2);        // 32 KB
  float* f2p = f1p + GN;                                  // 32 KB
  unsigned long long* mask = (unsigned long long*)(f2p + GN);  // 8 MB

  gat_k0<<<4096, 256, 0, stream>>>(adj, mask);
  gat_k1<<<256, 256, 0, stream>>>(input, W, a, hTt, f1p, f2p, out);
  gat_k2<<<512, 256, 0, stream>>>((const unsigned*)mask, hTt, f1p, f2p, out);
}

// Round 9
// 388.739 us; speedup vs baseline: 1.4581x; 1.3997x over previous
//
#include <hip/hip_runtime.h>
#include <hip/hip_bf16.h>

#define GN 8192
#define KD 256
#define OD 64
#define LOG2E 1.44269504f
#define ASTR 260   // adj LDS row stride (ints): 1040B, 16B-aligned, 2-way alias (free)
#define NCH 16     // 16 chunks x 256 j = 4096-j slice per block

typedef __attribute__((ext_vector_type(8))) short bf16x8;
typedef __attribute__((ext_vector_type(4))) float f32x4;

__device__ __forceinline__ float fexp2(float x) {
#if __has_builtin(__builtin_amdgcn_exp2f)
  return __builtin_amdgcn_exp2f(x);
#else
  return exp2f(x);
#endif
}

// ---------------------------------------------------------------------------
// Kernel 1: h = input @ W (fp32). Emits hTt (bf16, TILED [j/32][col][j%32] so
// k2's B-frag loads are contiguous 1KB bursts), f1p/f2p fp32 pre-scaled by
// log2(e), and the 3 scalar e-outputs.
// ---------------------------------------------------------------------------
__global__ __launch_bounds__(256) void gat_k1(
    const float* __restrict__ input, const float* __restrict__ W,
    const float* __restrict__ a, __hip_bfloat16* __restrict__ hTt,
    float* __restrict__ f1p, float* __restrict__ f2p, float* __restrict__ out)
{
  __shared__ float Wl[KD * OD];        // 64 KB, [k][c]
  __shared__ float inT[KD * 33];       // [k][r], pad 33
  __shared__ float red1[8][32];
  __shared__ float red2[8][32];
  __shared__ float s1row[32];
  __shared__ float s2row[32];

  const int tid = threadIdx.x;
  const int i0 = blockIdx.x * 32;      // this block's 32 j-rows == one j-tile

  for (int idx = tid; idx < KD * OD / 4; idx += 256)
    ((float4*)Wl)[idx] = ((const float4*)W)[idx];

#pragma unroll
  for (int it = 0; it < 8; ++it) {
    int idx = tid + it * 256;
    int r = idx >> 6, k4 = idx & 63;
    float4 v = *(const float4*)(input + (long)(i0 + r) * KD + k4 * 4);
    inT[(k4 * 4 + 0) * 33 + r] = v.x;
    inT[(k4 * 4 + 1) * 33 + r] = v.y;
    inT[(k4 * 4 + 2) * 33 + r] = v.z;
    inT[(k4 * 4 + 3) * 33 + r] = v.w;
  }
  __syncthreads();

  const int r = tid & 31;
  const int cg = tid >> 5;
  float acc[8];
#pragma unroll
  for (int c = 0; c < 8; ++c) acc[c] = 0.f;

#pragma unroll 4
  for (int k = 0; k < KD; ++k) {
    float inv = inT[k * 33 + r];
    float4 wa = *(const float4*)&Wl[k * 64 + cg * 8];
    float4 wb = *(const float4*)&Wl[k * 64 + cg * 8 + 4];
    acc[0] += inv * wa.x; acc[1] += inv * wa.y;
    acc[2] += inv * wa.z; acc[3] += inv * wa.w;
    acc[4] += inv * wb.x; acc[5] += inv * wb.y;
    acc[6] += inv * wb.z; acc[7] += inv * wb.w;
  }

  // hTt[jtile = i0/32][col][jw = r], two 16-j sub-tiles per 32: store as
  // [jt32][col][j%32] contiguous.
#pragma unroll
  for (int c = 0; c < 8; ++c)
    hTt[(long)blockIdx.x * (OD * 32) + (cg * 8 + c) * 32 + r] =
        __float2bfloat16(acc[c]);

  float s1 = 0.f, s2 = 0.f;
#pragma unroll
  for (int c = 0; c < 8; ++c) {
    s1 += acc[c] * a[cg * 8 + c];
    s2 += acc[c] * a[OD + cg * 8 + c];
  }
  red1[cg][r] = s1; red2[cg][r] = s2;
  __syncthreads();
  if (tid < 32) {
    float f1 = 0.f, f2 = 0.f;
#pragma unroll
    for (int g = 0; g < 8; ++g) { f1 += red1[g][tid]; f2 += red2[g][tid]; }
    s1row[tid] = f1; s2row[tid] = f2;
    f1p[i0 + tid] = f1 * LOG2E;
    f2p[i0 + tid] = f2 * LOG2E;
  }
  __syncthreads();
  if (blockIdx.x == 0 && tid == 0) {
    float e12 = s1row[1] + s2row[2];
    float e13 = s1row[1] + s2row[3];
    float e32 = s1row[3] + s2row[2];
    out[(long)GN * OD + 0] = fmaxf(e12, 0.01f * e12);
    out[(long)GN * OD + 1] = fmaxf(e13, 0.01f * e13);
    out[(long)GN * OD + 2] = fmaxf(e32, 0.01f * e32);
  }
}

// ---------------------------------------------------------------------------
// Kernel 2: fused mask+softmax(no-max)+alpha@h over a 4096-j slice.
// r4-proven LDS double-buffer staging of adj + two fixes:
//  (1) B-frags from TILED hTt -> each load is a contiguous 1KB burst;
//  (2) per-chunk vmem issue order: B(c) FIRST, then adj prefetch(c+1), so
//      the fine-grained vmcnt wait for B(c) leaves the prefetch in flight.
// f2 slice staged to LDS once. 1024 blocks = 512 rowgroups x 2 j-slices,
// 3 blocks/CU. Partial num/den to gmem; k3 combines.
// ---------------------------------------------------------------------------
__global__ __launch_bounds__(256, 3) void gat_k2(
    const int* __restrict__ adj, const __hip_bfloat16* __restrict__ hTt,
    const float* __restrict__ f1p, const float* __restrict__ f2p,
    float* __restrict__ pn, float* __restrict__ pd)
{
  __shared__ int abuf[2][16 * ASTR];   // 33.3 KB staged adj (dbuf)
  __shared__ float f2l[4096];          // 16 KB f2 slice
  // epilogue overlays partial buffers on abuf:
  float* pb = (float*)abuf;            // [4][16][68]
  float* sb = pb + 4 * 16 * 68;        // [4][16]

  const int tid = threadIdx.x;
  const int lane = tid & 63;
  const int wv = tid >> 6;             // wave -> k-steps {2wv, 2wv+1}
  const int tn = lane & 15;
  const int quad = lane >> 4;
  const int rg = blockIdx.x >> 1;
  const int js = blockIdx.x & 1;
  const int i0 = rg * 16;
  const int jbase = js * 4096;

  // stage f2 slice (16 KB)
  for (int i = tid; i < 4096 / 4; i += 256)
    ((float4*)f2l)[i] = ((const float4*)(f2p + jbase))[i];

  const float f1r = f1p[i0 + tn];

  // adj staging assignment: thread -> row sr, columns sc + 64k
  const int sr = tid >> 4;
  const int sc = (tid & 15) * 4;
  const int* gsrc = adj + (long)(i0 + sr) * GN + jbase + sc;

  // per-wave j-offsets within a 256-j chunk
  const int jo0 = wv * 64 + quad * 8;
  const int jo1 = jo0 + 32;
  // B-frag lane base inside a 32-j hTt slice
  const __hip_bfloat16* hsl = hTt + (long)(jbase / 32) * (OD * 32) + tn * 32 + quad * 8;

  f32x4 acc[4];
#pragma unroll
  for (int nf = 0; nf < 4; ++nf) acc[nf] = (f32x4){0.f, 0.f, 0.f, 0.f};
  f32x4 accS = (f32x4){0.f, 0.f, 0.f, 0.f};

  bf16x8 ones;  // ones in column n==0 -> row sums via MFMA
  {
    short ov = (tn == 0) ? (short)0x3F80 : (short)0;
#pragma unroll
    for (int i = 0; i < 8; ++i) ones[i] = ov;
  }

  int4 st[4];
  // prologue: stage chunk 0
#pragma unroll
  for (int k = 0; k < 4; ++k) st[k] = *(const int4*)(gsrc + 64 * k);
#pragma unroll
  for (int k = 0; k < 4; ++k) *(int4*)&abuf[0][sr * ASTR + sc + 64 * k] = st[k];
  __syncthreads();

  for (int c = 0; c < NCH; ++c) {
    const int cur = c & 1, nxt = cur ^ 1;

    // (1) B(c) loads FIRST: contiguous 1KB bursts from tiled hTt (L2-resident)
    const __hip_bfloat16* h0 = hsl + (long)(c * 8 + 2 * wv) * (OD * 32);
    const __hip_bfloat16* h1 = h0 + (OD * 32);
    bf16x8 B0[4], B1[4];
#pragma unroll
    for (int nf = 0; nf < 4; ++nf) {
      B0[nf] = *(const bf16x8*)(h0 + nf * (16 * 32));
      B1[nf] = *(const bf16x8*)(h1 + nf * (16 * 32));
    }

    // (2) THEN adj prefetch for chunk c+1 (stays in flight across B-waits)
    if (c + 1 < NCH) {
#pragma unroll
      for (int k = 0; k < 4; ++k)
        st[k] = *(const int4*)(gsrc + (c + 1) * 256 + 64 * k);
    }

    // A-source adj + f2 from LDS
    const int4 a0 = *(const int4*)&abuf[cur][tn * ASTR + jo0];
    const int4 a1 = *(const int4*)&abuf[cur][tn * ASTR + jo0 + 4];
    const int4 a2 = *(const int4*)&abuf[cur][tn * ASTR + jo1];
    const int4 a3 = *(const int4*)&abuf[cur][tn * ASTR + jo1 + 4];
    const float4 f20 = *(const float4*)&f2l[c * 256 + jo0];
    const float4 f21 = *(const float4*)&f2l[c * 256 + jo0 + 4];
    const float4 f22 = *(const float4*)&f2l[c * 256 + jo1];
    const float4 f23 = *(const float4*)&f2l[c * 256 + jo1 + 4];

    union { bf16x8 v; unsigned u[4]; } w0, w1;
    {
      float e0 = f1r + f20.x, e1 = f1r + f20.y, e2 = f1r + f20.z, e3 = f1r + f20.w;
      float e4 = f1r + f21.x, e5 = f1r + f21.y, e6 = f1r + f21.z, e7 = f1r + f21.w;
      float v0 = fexp2((a0.x > 0) ? fmaxf(e0, 0.01f * e0) : -256.f);
      float v1 = fexp2((a0.y > 0) ? fmaxf(e1, 0.01f * e1) : -256.f);
      float v2 = fexp2((a0.z > 0) ? fmaxf(e2, 0.01f * e2) : -256.f);
      float v3 = fexp2((a0.w > 0) ? fmaxf(e3, 0.01f * e3) : -256.f);
      float v4 = fexp2((a1.x > 0) ? fmaxf(e4, 0.01f * e4) : -256.f);
      float v5 = fexp2((a1.y > 0) ? fmaxf(e5, 0.01f * e5) : -256.f);
      float v6 = fexp2((a1.z > 0) ? fmaxf(e6, 0.01f * e6) : -256.f);
      float v7 = fexp2((a1.w > 0) ? fmaxf(e7, 0.01f * e7) : -256.f);
      w0.u[0] = __builtin_amdgcn_perm(__float_as_uint(v1), __float_as_uint(v0), 0x07060302u);
      w0.u[1] = __builtin_amdgcn_perm(__float_as_uint(v3), __float_as_uint(v2), 0x07060302u);
      w0.u[2] = __builtin_amdgcn_perm(__float_as_uint(v5), __float_as_uint(v4), 0x07060302u);
      w0.u[3] = __builtin_amdgcn_perm(__float_as_uint(v7), __float_as_uint(v6), 0x07060302u);
    }
    {
      float e0 = f1r + f22.x, e1 = f1r + f22.y, e2 = f1r + f22.z, e3 = f1r + f22.w;
      float e4 = f1r + f23.x, e5 = f1r + f23.y, e6 = f1r + f23.z, e7 = f1r + f23.w;
      float v0 = fexp2((a2.x > 0) ? fmaxf(e0, 0.01f * e0) : -256.f);
      float v1 = fexp2((a2.y > 0) ? fmaxf(e1, 0.01f * e1) : -256.f);
      float v2 = fexp2((a2.z > 0) ? fmaxf(e2, 0.01f * e2) : -256.f);
      float v3 = fexp2((a2.w > 0) ? fmaxf(e3, 0.01f * e3) : -256.f);
      float v4 = fexp2((a3.x > 0) ? fmaxf(e4, 0.01f * e4) : -256.f);
      float v5 = fexp2((a3.y > 0) ? fmaxf(e5, 0.01f * e5) : -256.f);
      float v6 = fexp2((a3.z > 0) ? fmaxf(e6, 0.01f * e6) : -256.f);
      float v7 = fexp2((a3.w > 0) ? fmaxf(e7, 0.01f * e7) : -256.f);
      w1.u[0] = __builtin_amdgcn_perm(__float_as_uint(v1), __float_as_uint(v0), 0x07060302u);
      w1.u[1] = __builtin_amdgcn_perm(__float_as_uint(v3), __float_as_uint(v2), 0x07060302u);
      w1.u[2] = __builtin_amdgcn_perm(__float_as_uint(v5), __float_as_uint(v4), 0x07060302u);
      w1.u[3] = __builtin_amdgcn_perm(__float_as_uint(v7), __float_as_uint(v6), 0x07060302u);
    }

#pragma unroll
    for (int nf = 0; nf < 4; ++nf)
      acc[nf] = __builtin_amdgcn_mfma_f32_16x16x32_bf16(w0.v, B0[nf], acc[nf], 0, 0, 0);
    accS = __builtin_amdgcn_mfma_f32_16x16x32_bf16(w0.v, ones, accS, 0, 0, 0);
#pragma unroll
    for (int nf = 0; nf < 4; ++nf)
      acc[nf] = __builtin_amdgcn_mfma_f32_16x16x32_bf16(w1.v, B1[nf], acc[nf], 0, 0, 0);
    accS = __builtin_amdgcn_mfma_f32_16x16x32_bf16(w1.v, ones, accS, 0, 0, 0);

    if (c + 1 < NCH) {  // commit staged chunk c+1 (waits only on its own loads)
#pragma unroll
      for (int k = 0; k < 4; ++k)
        *(int4*)&abuf[nxt][sr * ASTR + sc + 64 * k] = st[k];
    }
    __syncthreads();
  }

  // epilogue: reduce the 4 wave K-partials in LDS (overlaid), write partials
#pragma unroll
  for (int nf = 0; nf < 4; ++nf)
#pragma unroll
    for (int rgi = 0; rgi < 4; ++rgi)
      pb[(wv * 16 + quad * 4 + rgi) * 68 + nf * 16 + tn] = acc[nf][rgi];
  if (tn == 0) {
#pragma unroll
    for (int rgi = 0; rgi < 4; ++rgi)
      sb[wv * 16 + quad * 4 + rgi] = accS[rgi];
  }
  __syncthreads();
  for (int t = tid; t < 16 * OD; t += 256) {
    int rr = t >> 6, cc = t & 63;
    float num = pb[(0 * 16 + rr) * 68 + cc] + pb[(1 * 16 + rr) * 68 + cc] +
                pb[(2 * 16 + rr) * 68 + cc] + pb[(3 * 16 + rr) * 68 + cc];
    pn[((long)js * GN + i0 + rr) * OD + cc] = num;
  }
  if (tid < 16) {
    float den = sb[0 * 16 + tid] + sb[1 * 16 + tid] + sb[2 * 16 + tid] + sb[3 * 16 + tid];
    pd[(long)js * GN + i0 + tid] = den;
  }
}

// ---------------------------------------------------------------------------
// Kernel 3: combine the 2 j-slices: out = (pn0+pn1)/(pd0+pd1)
// ---------------------------------------------------------------------------
__global__ __launch_bounds__(256) void gat_k3(
    const float* __restrict__ pn, const float* __restrict__ pd,
    float* __restrict__ out)
{
  long t = (long)blockIdx.x * 256 + threadIdx.x;   // 0 .. GN*OD
  int i = (int)(t >> 6);
  float num = pn[t] + pn[(long)GN * OD + t];
  float den = pd[i] + pd[GN + i];
  out[t] = num / den;
}

extern "C" void kernel_launch(void* const* d_in, const int* in_sizes, int n_in,
                              void* d_out, int out_size, void* d_ws, size_t ws_size,
                              hipStream_t stream) {
  const float* input = (const float*)d_in[0];
  const int* adj     = (const int*)d_in[1];
  const float* W     = (const float*)d_in[2];
  const float* a     = (const float*)d_in[3];
  float* out = (float*)d_out;

  char* ws = (char*)d_ws;
  __hip_bfloat16* hTt = (__hip_bfloat16*)ws;              // 1 MB (tiled)
  float* f1p = (float*)(ws + (size_t)OD * GN * 2);        // 32 KB
  float* f2p = f1p + GN;                                  // 32 KB
  float* pn  = f2p + GN;                                  // 4 MB
  float* pd  = pn + (size_t)2 * GN * OD;                  // 64 KB

  gat_k1<<<256, 256, 0, stream>>>(input, W, a, hTt, f1p, f2p, out);
  gat_k2<<<1024, 256, 0, stream>>>(adj, hTt, f1p, f2p, pn, pd);
  gat_k3<<<GN * OD / 256, 256, 0, stream>>>(pn, pd, out);
}